// Round 6
// baseline (391.030 us; speedup 1.0000x reference)
//
#include <hip/hip_runtime.h>
#include <hip/hip_bf16.h>
#include <stdint.h>

// Problem constants (fixed by setup_inputs)
constexpr int Bn  = 8;
constexpr int Cc  = 512;
constexpr int ICc = 256;
constexpr int HWc = 48 * 48;           // 2304
constexpr float BN_EPS = 1e-5f;
constexpr int NSPLIT = 3;              // flash key-splits
constexpr int KSP = HWc / NSPLIT;      // 768 keys per split
constexpr int NKT = KSP / 64;          // 12 key-tiles of 64

typedef unsigned short u16;
typedef __attribute__((ext_vector_type(8))) short short8;   // 8 bf16 (4 VGPRs)
typedef __attribute__((ext_vector_type(4))) float f32x4;    // MFMA C/D frag

__device__ __forceinline__ u16 f2bf(float f) {
    uint32_t u = __builtin_bit_cast(uint32_t, f);
    u += 0x7fffu + ((u >> 16) & 1u);     // RNE
    return (u16)(u >> 16);
}
// async global->LDS, 16B per lane; lds dst is wave-uniform base (HW adds lane*16)
__device__ __forceinline__ void load_lds16(const void* g, void* l) {
    __builtin_amdgcn_global_load_lds(
        (const __attribute__((address_space(1))) void*)(uintptr_t)g,
        (__attribute__((address_space(3))) void*)(uintptr_t)l, 16, 0, 0);
}

// ---------------------------------------------------------------------------
// Front cast: thph_w bf16 (rows 0..255=th_w, 256..511=ph_w), g_w bf16,
// bias_thph fp32 [th_b | ph_b].
// ---------------------------------------------------------------------------
__global__ __launch_bounds__(256)
void cast_front(const float* __restrict__ th_w, const float* __restrict__ ph_w,
                const float* __restrict__ g_w, const float* __restrict__ th_b,
                const float* __restrict__ ph_b, u16* __restrict__ wcat,
                float* __restrict__ bias_thph) {
    int idx = blockIdx.x * 256 + threadIdx.x;
    if (idx < 98304) {                           // ushort4 casts
        const float4* src;
        if (idx < 32768)       src = (const float4*)th_w + idx;
        else if (idx < 65536)  src = (const float4*)ph_w + (idx - 32768);
        else                   src = (const float4*)g_w  + (idx - 65536);
        float4 v = *src;
        ushort4 o;
        o.x = f2bf(v.x); o.y = f2bf(v.y); o.z = f2bf(v.z); o.w = f2bf(v.w);
        ((ushort4*)wcat)[idx] = o;
    } else if (idx < 98816) {                    // 512 bias floats
        int i = idx - 98304;
        bias_thph[i] = (i < 256) ? th_b[i] : ph_b[i - 256];
    }
}

__global__ __launch_bounds__(256)
void cast_w(const float* __restrict__ a, u16* __restrict__ out) {
    int idx = blockIdx.x * 256 + threadIdx.x;    // 0..32767
    float4 v = ((const float4*)a)[idx];
    ushort4 o;
    o.x = f2bf(v.x); o.y = f2bf(v.y); o.z = f2bf(v.z); o.w = f2bf(v.w);
    ((ushort4*)out)[idx] = o;
}

// ---------------------------------------------------------------------------
// x (B,C,HW) fp32 -> xt (B,HW,C) bf16, 64c x 32p LDS-tiled, ushort2 stores
// ---------------------------------------------------------------------------
__global__ __launch_bounds__(256)
void transpose_cast_x(const float* __restrict__ x, u16* __restrict__ xt) {
    __shared__ float t[64][33];
    const int b = blockIdx.z;
    const int p0 = blockIdx.x * 32;     // HW dir
    const int c0 = blockIdx.y * 64;     // C dir
    const int tx = threadIdx.x & 31, ty = threadIdx.x >> 5;   // ty 0..7
    const float* xb = x + (size_t)b * Cc * HWc;
#pragma unroll
    for (int r = 0; r < 8; ++r)
        t[r * 8 + ty][tx] = xb[(size_t)(c0 + r * 8 + ty) * HWc + p0 + tx];
    __syncthreads();
    u16* xtb = xt + (size_t)b * HWc * Cc;
    const int cc = (threadIdx.x & 31) * 2, pp = threadIdx.x >> 5;
#pragma unroll
    for (int r = 0; r < 4; ++r) {
        int p = r * 8 + pp;
        ushort2 v;
        v.x = f2bf(t[cc][p]);
        v.y = f2bf(t[cc + 1][p]);
        *(ushort2*)&xtb[(size_t)(p0 + p) * Cc + c0 + cc] = v;
    }
}

// ---------------------------------------------------------------------------
// bf16 MFMA GEMM: C[m][n] = sum_k A[m][k] * B[n][k] (+ bias)
// TM=128 or 64; STORE 0=bf16, 1=fp32; STATS: fused BN sum/sumsq per m.
// ---------------------------------------------------------------------------
template <int TM, int STORE, bool STATS>
__global__ __launch_bounds__(256, 2)
void mfma_gemm(const u16* __restrict__ A, const u16* __restrict__ B,
               void* __restrict__ Cout, const float* __restrict__ bias,
               int bias_mode, int K, int ldA, int ldB, int ldC,
               size_t sA, size_t sB, size_t sC,
               float* __restrict__ s0g, float* __restrict__ s1g) {
    constexpr int MI = TM / 32;                  // 4 (TM=128) or 2 (TM=64)
    __shared__ __align__(16) u16 As[TM * 32];
    __shared__ __align__(16) u16 Bs[128 * 32];
    const int bz = blockIdx.z;
    const int m0 = blockIdx.y * TM, n0 = blockIdx.x * 128;
    const u16* Ab = A + (size_t)bz * sA + (size_t)m0 * ldA;
    const u16* Bb = B + (size_t)bz * sB + (size_t)n0 * ldB;
    const int tid = threadIdx.x, lane = tid & 63, w = tid >> 6;
    const int wm = (w & 1) * (TM / 2);
    const int wn = (w >> 1) * 64;
    const int quad = lane >> 4, m16 = lane & 15;

    f32x4 acc[MI][4];
#pragma unroll
    for (int i = 0; i < MI; ++i)
#pragma unroll
        for (int j = 0; j < 4; ++j) acc[i][j] = (f32x4){0.f, 0.f, 0.f, 0.f};

    const int L0 = 2 * w * 64 + lane, L1 = L0 + 64;
    const int br0 = L0 >> 2, bc0 = (L0 & 3) * 8;
    const int br1 = L1 >> 2, bc1 = (L1 & 3) * 8;
    const int ar0 = (TM == 128) ? br0 : (tid >> 2);
    const int ac0 = (TM == 128) ? bc0 : (tid & 3) * 8;

    for (int k0 = 0; k0 < K; k0 += 32) {
        if (TM == 128) {
            load_lds16(Ab + (size_t)ar0 * ldA + k0 + ac0, &As[2 * w * 512]);
            load_lds16(Ab + (size_t)br1 * ldA + k0 + bc1, &As[(2 * w + 1) * 512]);
        } else {
            load_lds16(Ab + (size_t)ar0 * ldA + k0 + ac0, &As[w * 512]);
        }
        load_lds16(Bb + (size_t)br0 * ldB + k0 + bc0, &Bs[2 * w * 512]);
        load_lds16(Bb + (size_t)br1 * ldB + k0 + bc1, &Bs[(2 * w + 1) * 512]);
        __syncthreads();

        short8 af[MI], bfv[4];
#pragma unroll
        for (int i = 0; i < MI; ++i)
            af[i] = *(const short8*)&As[(wm + i * 16 + m16) * 32 + quad * 8];
#pragma unroll
        for (int j = 0; j < 4; ++j)
            bfv[j] = *(const short8*)&Bs[(wn + j * 16 + m16) * 32 + quad * 8];
#pragma unroll
        for (int i = 0; i < MI; ++i)
#pragma unroll
            for (int j = 0; j < 4; ++j)
                acc[i][j] = __builtin_amdgcn_mfma_f32_16x16x32_bf16(
                    af[i], bfv[j], acc[i][j], 0, 0, 0);
        __syncthreads();
    }

    if (bias_mode) {
#pragma unroll
        for (int i = 0; i < MI; ++i)
#pragma unroll
            for (int j = 0; j < 4; ++j)
#pragma unroll
                for (int r = 0; r < 4; ++r)
                    acc[i][j][r] += (bias_mode == 2)
                        ? bias[m0 + wm + i * 16 + quad * 4 + r]
                        : bias[n0 + wn + j * 16 + m16];
    }

    if (STORE == 0) {
        u16* C = (u16*)Cout + (size_t)bz * sC;
#pragma unroll
        for (int i = 0; i < MI; ++i) {
            int m = m0 + wm + i * 16 + quad * 4;
#pragma unroll
            for (int j = 0; j < 4; ++j) {
                int n = n0 + wn + j * 16 + m16;
#pragma unroll
                for (int r = 0; r < 4; ++r)
                    C[(size_t)(m + r) * ldC + n] = f2bf(acc[i][j][r]);
            }
        }
    } else {
        float* C = (float*)Cout + (size_t)bz * sC;
#pragma unroll
        for (int i = 0; i < MI; ++i) {
            int m = m0 + wm + i * 16 + quad * 4;
#pragma unroll
            for (int j = 0; j < 4; ++j) {
                int n = n0 + wn + j * 16 + m16;
#pragma unroll
                for (int r = 0; r < 4; ++r)
                    C[(size_t)(m + r) * ldC + n] = acc[i][j][r];
            }
        }
    }

    if (STATS) {
#pragma unroll
        for (int i = 0; i < MI; ++i) {
#pragma unroll
            for (int r = 0; r < 4; ++r) {
                float v0 = 0.f, v1 = 0.f;
#pragma unroll
                for (int j = 0; j < 4; ++j) {
                    float v = acc[i][j][r];
                    v0 += v;
                    v1 = fmaf(v, v, v1);
                }
#pragma unroll
                for (int off = 8; off; off >>= 1) {
                    v0 += __shfl_down(v0, off, 16);
                    v1 += __shfl_down(v1, off, 16);
                }
                if (m16 == 0) {
                    int m = m0 + wm + i * 16 + quad * 4 + r;
                    atomicAdd(&s0g[m], v0);
                    atomicAdd(&s1g[m], v1);
                }
            }
        }
    }
}

// ---------------------------------------------------------------------------
// Split-K flash attention. Each block: 64 queries x 768 keys (split of 3).
//   thph: (B, HW, 512) bf16 — theta cols 0..255 (Q), phi cols 256..511 (K)
//   g   : (B, IC, HW)  bf16 (V; rows ic, cols key)
// Outputs (per split): Opart fp32 (S,B,HW,IC) unnormalized, mpart/lpart (S,B,HW).
// 4 waves; wave w owns queries [q0+16w, +16). Per 64-key tile: stage K 32KB ->
// QK (32 MFMA/wave) -> online softmax -> P via per-wave private LDS ->
// stage V 32KB (same buffer) -> PV (32 MFMA/wave). 4 barriers per tile.
// LDS: buf 16384 u16 (32KB, K/V/Q staging) + 4x1088 u16 P = 41.5KB -> 3 blk/CU.
// ---------------------------------------------------------------------------
__global__ __launch_bounds__(256, 3)
void flash_attn(const u16* __restrict__ thph, const u16* __restrict__ g,
                float* __restrict__ Opart, float* __restrict__ mpart,
                float* __restrict__ lpart) {
    __shared__ __align__(16) u16 smem[16384 + 4 * 1088];
    const int bz = blockIdx.z, split = blockIdx.y;
    const int q0 = blockIdx.x * 64;
    const int ks = split * KSP;
    const u16* Qb = thph + (size_t)bz * HWc * 512 + (size_t)q0 * 512;
    const u16* Kb = thph + (size_t)bz * HWc * 512 + 256;
    const u16* Vb = g + (size_t)bz * ICc * HWc;
    const int tid = threadIdx.x, lane = tid & 63, w = tid >> 6;
    const int quad = lane >> 4, m16 = lane & 15;
    const int wm = w * 16;
    u16* Pw = &smem[16384 + w * 1088];

    // ---- stage Q (64 rows x 256 dims, chunk-major 8 x (64x32)) ----
#pragma unroll
    for (int it = 0; it < 8; ++it) {
        int L = it * 256 + tid;
        int c = L >> 8, s = L & 255;
        load_lds16(Qb + (size_t)(s >> 2) * 512 + c * 32 + (s & 3) * 8,
                   &smem[(it * 256 + w * 64) * 8]);
    }
    __syncthreads();
    short8 qf[8];
#pragma unroll
    for (int c = 0; c < 8; ++c)
        qf[c] = *(const short8*)&smem[c * 2048 + (wm + m16) * 32 + quad * 8];

    f32x4 O[16];
#pragma unroll
    for (int i = 0; i < 16; ++i) O[i] = (f32x4){0.f, 0.f, 0.f, 0.f};
    float mrow[4] = {-1e30f, -1e30f, -1e30f, -1e30f};
    float lrow[4] = {0.f, 0.f, 0.f, 0.f};

    for (int kt = 0; kt < NKT; ++kt) {
        const u16* Kt = Kb + (size_t)(ks + kt * 64) * 512;
        __syncthreads();                 // prior buf consumers done (qf/PV)
#pragma unroll
        for (int it = 0; it < 8; ++it) {
            int L = it * 256 + tid;
            int c = L >> 8, s = L & 255;
            load_lds16(Kt + (size_t)(s >> 2) * 512 + c * 32 + (s & 3) * 8,
                       &smem[(it * 256 + w * 64) * 8]);
        }
        __syncthreads();                 // K visible

        f32x4 Sa[4];
#pragma unroll
        for (int j = 0; j < 4; ++j) Sa[j] = (f32x4){0.f, 0.f, 0.f, 0.f};
#pragma unroll
        for (int kc = 0; kc < 8; ++kc)
#pragma unroll
            for (int j = 0; j < 4; ++j) {
                short8 kf = *(const short8*)
                    &smem[kc * 2048 + (j * 16 + m16) * 32 + quad * 8];
                Sa[j] = __builtin_amdgcn_mfma_f32_16x16x32_bf16(
                    qf[kc], kf, Sa[j], 0, 0, 0);
            }

        // ---- online softmax (col key = m16 + 16j, row q = quad*4 + r) ----
        float alpha[4];
#pragma unroll
        for (int r = 0; r < 4; ++r) {
            float tm = Sa[0][r];
#pragma unroll
            for (int j = 1; j < 4; ++j) tm = fmaxf(tm, Sa[j][r]);
#pragma unroll
            for (int off = 1; off < 16; off <<= 1)
                tm = fmaxf(tm, __shfl_xor(tm, off, 16));
            float nm = fmaxf(mrow[r], tm);
            alpha[r] = __expf(mrow[r] - nm);
            mrow[r] = nm;
            float ps = 0.f;
#pragma unroll
            for (int j = 0; j < 4; ++j) {
                float p = __expf(Sa[j][r] - nm);
                Sa[j][r] = p;
                ps += p;
            }
#pragma unroll
            for (int off = 1; off < 16; off <<= 1)
                ps += __shfl_xor(ps, off, 16);
            lrow[r] = lrow[r] * alpha[r] + ps;
        }
#pragma unroll
        for (int j2 = 0; j2 < 16; ++j2)
#pragma unroll
            for (int r = 0; r < 4; ++r) O[j2][r] *= alpha[r];

        // ---- P: C-layout -> A-layout, per-wave private (no barrier) ----
#pragma unroll
        for (int j = 0; j < 4; ++j)
#pragma unroll
            for (int r = 0; r < 4; ++r)
                Pw[(j >> 1) * 512 + (quad * 4 + r) * 32 + (j & 1) * 16 + m16] =
                    f2bf(Sa[j][r]);
        short8 pf[2];
#pragma unroll
        for (int c2 = 0; c2 < 2; ++c2)
            pf[c2] = *(const short8*)&Pw[c2 * 512 + m16 * 32 + quad * 8];

        __syncthreads();                 // all waves done reading K
        // ---- stage V (256 ic x 64 keys, chunk-major 2 x (256x32)) ----
        const u16* Vt = Vb + ks + kt * 64;
#pragma unroll
        for (int it = 0; it < 8; ++it) {
            int L = it * 256 + tid;
            int c2 = L >> 10, s = L & 1023;
            load_lds16(Vt + (size_t)(s >> 2) * HWc + c2 * 32 + (s & 3) * 8,
                       &smem[(it * 256 + w * 64) * 8]);
        }
        __syncthreads();                 // V visible

#pragma unroll
        for (int c2 = 0; c2 < 2; ++c2)
#pragma unroll
            for (int j2 = 0; j2 < 16; ++j2) {
                short8 vf = *(const short8*)
                    &smem[c2 * 8192 + (j2 * 16 + m16) * 32 + quad * 8];
                O[j2] = __builtin_amdgcn_mfma_f32_16x16x32_bf16(
                    pf[c2], vf, O[j2], 0, 0, 0);
            }
    }

    // ---- epilogue: unnormalized O + (m, l) per row ----
    float* Ob = Opart + ((size_t)(split * Bn + bz) * HWc + q0 + wm) * ICc;
#pragma unroll
    for (int j2 = 0; j2 < 16; ++j2)
#pragma unroll
        for (int r = 0; r < 4; ++r)
            Ob[(size_t)(quad * 4 + r) * ICc + j2 * 16 + m16] = O[j2][r];
    if (m16 == 0) {
#pragma unroll
        for (int r = 0; r < 4; ++r) {
            size_t idx = (size_t)(split * Bn + bz) * HWc + q0 + wm + quad * 4 + r;
            mpart[idx] = mrow[r];
            lpart[idx] = lrow[r];
        }
    }
}

// ---------------------------------------------------------------------------
// Combine NSPLIT partials -> y bf16 (B, HW, IC)
// ---------------------------------------------------------------------------
__global__ __launch_bounds__(256)
void flash_combine(const float* __restrict__ Opart, const float* __restrict__ mpart,
                   const float* __restrict__ lpart, u16* __restrict__ y) {
    const int b = blockIdx.y;
    const int q = blockIdx.x * 4 + (threadIdx.x >> 6);
    const int ic = (threadIdx.x & 63) * 4;
    const size_t rq = (size_t)b * HWc + q;
    const size_t SS = (size_t)Bn * HWc;

    float m0 = mpart[rq], m1 = mpart[SS + rq], m2 = mpart[2 * SS + rq];
    float M = fmaxf(m0, fmaxf(m1, m2));
    float w0 = __expf(m0 - M), w1 = __expf(m1 - M), w2 = __expf(m2 - M);
    float L = lpart[rq] * w0 + lpart[SS + rq] * w1 + lpart[2 * SS + rq] * w2;
    float inv = 1.0f / L;
    w0 *= inv; w1 *= inv; w2 *= inv;

    f32x4 o0 = *(const f32x4*)&Opart[rq * ICc + ic];
    f32x4 o1 = *(const f32x4*)&Opart[(SS + rq) * ICc + ic];
    f32x4 o2 = *(const f32x4*)&Opart[(2 * SS + rq) * ICc + ic];
    ushort4 o;
    o.x = f2bf(o0[0] * w0 + o1[0] * w1 + o2[0] * w2);
    o.y = f2bf(o0[1] * w0 + o1[1] * w1 + o2[1] * w2);
    o.z = f2bf(o0[2] * w0 + o1[2] * w1 + o2[2] * w2);
    o.w = f2bf(o0[3] * w0 + o1[3] * w1 + o2[3] * w2);
    *(ushort4*)&y[rq * ICc + ic] = o;
}

// ---------------------------------------------------------------------------
// Normalize (from raw sums) + affine + residual, float4 vectorized
// ---------------------------------------------------------------------------
__global__ __launch_bounds__(256)
void bn_apply(const float* __restrict__ wy, const float* __restrict__ x,
              const float* __restrict__ s0, const float* __restrict__ s1,
              const float* __restrict__ gamma, const float* __restrict__ beta,
              float* __restrict__ out) {
    const size_t i4 = (size_t)blockIdx.x * 256 + threadIdx.x;
    const size_t base = i4 * 4;
    const int o = (int)((base / HWc) % Cc);
    const float N = (float)(Bn * HWc);
    const float mean = s0[o] / N;
    const float var  = s1[o] / N - mean * mean;
    const float rstd = rsqrtf(var + BN_EPS);
    const float ga = gamma[o];
    const float be = beta[o];
    const float4 w4 = ((const float4*)wy)[i4];
    const float4 x4 = ((const float4*)x)[i4];
    float4 r;
    r.x = (w4.x - mean) * rstd * ga + be + x4.x;
    r.y = (w4.y - mean) * rstd * ga + be + x4.y;
    r.z = (w4.z - mean) * rstd * ga + be + x4.z;
    r.w = (w4.w - mean) * rstd * ga + be + x4.w;
    ((float4*)out)[i4] = r;
}

// ---------------------------------------------------------------------------
extern "C" void kernel_launch(void* const* d_in, const int* in_sizes, int n_in,
                              void* d_out, int out_size, void* d_ws, size_t ws_size,
                              hipStream_t stream) {
    const float* x     = (const float*)d_in[0];
    const float* g_w   = (const float*)d_in[1];
    const float* g_b   = (const float*)d_in[2];
    const float* th_w  = (const float*)d_in[3];
    const float* th_b  = (const float*)d_in[4];
    const float* ph_w  = (const float*)d_in[5];
    const float* ph_b  = (const float*)d_in[6];
    const float* w_w   = (const float*)d_in[7];
    const float* w_b   = (const float*)d_in[8];
    const float* gamma = (const float*)d_in[9];
    const float* beta  = (const float*)d_in[10];

    // Workspace layout (peak 95.9 MB < proven 113.25 MB bound):
    //  static: thph, g, y, wbf2, stats, bias_thph, wcat
    //  region R (38,803,456): xt (front) -> Opart+m+l (flash) -> wy (tail)
    char* base = (char*)d_ws;
    u16* thph = (u16*)base;                               // 18,874,368
    u16* g    = (u16*)(base + 18874368);                  //  9,437,184
    u16* y    = (u16*)(base + 28311552);                  //  9,437,184
    u16* wbf2 = (u16*)(base + 37748736);                  //    262,144
    float* stats = (float*)(base + 38010880);             //      4,096
    float* bias_thph = (float*)(base + 38014976);         //      2,048
    u16* wcat = (u16*)(base + 38017024);                  //    786,432
    char* R   = base + 38803456;
    u16* xt   = (u16*)R;                                  // 18,874,368
    float* Opart = (float*)R;                             // 56,623,104
    float* mpart = (float*)(R + 56623104);                //    221,184
    float* lpart = (float*)(R + 56844288);                //    221,184
    float* wy = (float*)R;                                // 37,748,736

    dim3 blk(256);
    const u16* thphw = wcat;                   // (512,512)
    const u16* gwb   = wcat + 262144;          // (256,512)

    cast_front<<<dim3(386), blk, 0, stream>>>(th_w, ph_w, g_w, th_b, ph_b,
                                              wcat, bias_thph);
    cast_w<<<dim3(128), blk, 0, stream>>>(w_w, wbf2);
    hipMemsetAsync(stats, 0, 2 * Cc * sizeof(float), stream);
    transpose_cast_x<<<dim3(HWc / 32, Cc / 64, Bn), blk, 0, stream>>>(x, xt);

    // thph[q][o] = sum_c xt[q][c]*thph_w[o][c] + bias  (M=2304,N=512,K=512)
    mfma_gemm<128, 0, false><<<dim3(4, 18, Bn), blk, 0, stream>>>(
        xt, thphw, thph, bias_thph, 1, Cc, Cc, Cc, 512,
        (size_t)HWc * Cc, 0, (size_t)HWc * 512, nullptr, nullptr);

    // g[ic][p] = sum_c g_w[ic][c]*xt[p][c] + g_b[ic]   (M=256,N=2304,K=512)
    mfma_gemm<64, 0, false><<<dim3(18, 4, Bn), blk, 0, stream>>>(
        gwb, xt, g, g_b, 2, Cc, Cc, Cc, HWc,
        0, (size_t)HWc * Cc, (size_t)ICc * HWc, nullptr, nullptr);

    // split-K fused attention -> partials, then combine -> y
    flash_attn<<<dim3(HWc / 64, NSPLIT, Bn), blk, 0, stream>>>(
        thph, g, Opart, mpart, lpart);
    flash_combine<<<dim3(HWc / 4, Bn), blk, 0, stream>>>(Opart, mpart, lpart, y);

    // wy[o][p] = sum_ic w_w[o][ic]*y[p][ic] + w_b[o]  (M=512,N=2304,K=256)
    // fp32 out + fused BN sum/sumsq
    mfma_gemm<128, 1, true><<<dim3(18, 4, Bn), blk, 0, stream>>>(
        wbf2, y, wy, w_b, 2, ICc, ICc, ICc, HWc,
        0, (size_t)HWc * ICc, (size_t)Cc * HWc, stats, stats + Cc);

    // BatchNorm apply (stats from raw sums) + affine + residual
    bn_apply<<<dim3((Bn * Cc * HWc) / 4 / 256), blk, 0, stream>>>(
        wy, x, stats, stats + Cc, gamma, beta, (float*)d_out);
}

// Round 7
// 387.793 us; speedup vs baseline: 1.0083x; 1.0083x over previous
//
#include <hip/hip_runtime.h>
#include <hip/hip_bf16.h>
#include <stdint.h>

// Problem constants (fixed by setup_inputs)
constexpr int Bn  = 8;
constexpr int Cc  = 512;
constexpr int ICc = 256;
constexpr int HWc = 48 * 48;           // 2304
constexpr float BN_EPS = 1e-5f;

typedef unsigned short u16;
typedef __attribute__((ext_vector_type(8))) short short8;   // 8 bf16 (4 VGPRs)
typedef __attribute__((ext_vector_type(4))) float f32x4;    // MFMA C/D frag

__device__ __forceinline__ u16 f2bf(float f) {
    uint32_t u = __builtin_bit_cast(uint32_t, f);
    u += 0x7fffu + ((u >> 16) & 1u);     // RNE
    return (u16)(u >> 16);
}
__device__ __forceinline__ float bf2f(u16 h) {
    uint32_t u = ((uint32_t)h) << 16;
    return __builtin_bit_cast(float, u);
}
// async global->LDS, 16B per lane; lds dst is wave-uniform base (HW adds lane*16)
__device__ __forceinline__ void load_lds16(const void* g, void* l) {
    __builtin_amdgcn_global_load_lds(
        (const __attribute__((address_space(1))) void*)(uintptr_t)g,
        (__attribute__((address_space(3))) void*)(uintptr_t)l, 16, 0, 0);
}

// ---------------------------------------------------------------------------
// Front cast: thph_w bf16 (rows 0..255=th_w, 256..511=ph_w), g_w bf16,
// bias_thph fp32 [th_b | ph_b].
// ---------------------------------------------------------------------------
__global__ __launch_bounds__(256)
void cast_front(const float* __restrict__ th_w, const float* __restrict__ ph_w,
                const float* __restrict__ g_w, const float* __restrict__ th_b,
                const float* __restrict__ ph_b, u16* __restrict__ wcat,
                float* __restrict__ bias_thph) {
    int idx = blockIdx.x * 256 + threadIdx.x;
    if (idx < 98304) {                           // ushort4 casts
        const float4* src;
        if (idx < 32768)       src = (const float4*)th_w + idx;
        else if (idx < 65536)  src = (const float4*)ph_w + (idx - 32768);
        else                   src = (const float4*)g_w  + (idx - 65536);
        float4 v = *src;
        ushort4 o;
        o.x = f2bf(v.x); o.y = f2bf(v.y); o.z = f2bf(v.z); o.w = f2bf(v.w);
        ((ushort4*)wcat)[idx] = o;
    } else if (idx < 98816) {                    // 512 bias floats
        int i = idx - 98304;
        bias_thph[i] = (i < 256) ? th_b[i] : ph_b[i - 256];
    }
}

__global__ __launch_bounds__(256)
void cast_w(const float* __restrict__ a, u16* __restrict__ out) {
    int idx = blockIdx.x * 256 + threadIdx.x;    // 0..32767
    float4 v = ((const float4*)a)[idx];
    ushort4 o;
    o.x = f2bf(v.x); o.y = f2bf(v.y); o.z = f2bf(v.z); o.w = f2bf(v.w);
    ((ushort4*)out)[idx] = o;
}

// ---------------------------------------------------------------------------
// x (B,C,HW) fp32 -> xt (B,HW,C) bf16, 64c x 32p LDS-tiled, ushort2 stores
// ---------------------------------------------------------------------------
__global__ __launch_bounds__(256)
void transpose_cast_x(const float* __restrict__ x, u16* __restrict__ xt) {
    __shared__ float t[64][33];
    const int b = blockIdx.z;
    const int p0 = blockIdx.x * 32;     // HW dir
    const int c0 = blockIdx.y * 64;     // C dir
    const int tx = threadIdx.x & 31, ty = threadIdx.x >> 5;   // ty 0..7
    const float* xb = x + (size_t)b * Cc * HWc;
#pragma unroll
    for (int r = 0; r < 8; ++r)
        t[r * 8 + ty][tx] = xb[(size_t)(c0 + r * 8 + ty) * HWc + p0 + tx];
    __syncthreads();
    u16* xtb = xt + (size_t)b * HWc * Cc;
    const int cc = (threadIdx.x & 31) * 2, pp = threadIdx.x >> 5;
#pragma unroll
    for (int r = 0; r < 4; ++r) {
        int p = r * 8 + pp;
        ushort2 v;
        v.x = f2bf(t[cc][p]);
        v.y = f2bf(t[cc + 1][p]);
        *(ushort2*)&xtb[(size_t)(p0 + p) * Cc + c0 + cc] = v;
    }
}

// ---------------------------------------------------------------------------
// bf16 MFMA GEMM: C[m][n] = sum_k A[m][k] * B[n][k] (+ bias)
// TM=128 or 64; STORE 0=bf16, 1=fp32; STATS: fused BN sum/sumsq per m.
// ---------------------------------------------------------------------------
template <int TM, int STORE, bool STATS>
__global__ __launch_bounds__(256, 2)
void mfma_gemm(const u16* __restrict__ A, const u16* __restrict__ B,
               void* __restrict__ Cout, const float* __restrict__ bias,
               int bias_mode, int K, int ldA, int ldB, int ldC,
               size_t sA, size_t sB, size_t sC,
               float* __restrict__ s0g, float* __restrict__ s1g) {
    constexpr int MI = TM / 32;                  // 4 (TM=128) or 2 (TM=64)
    __shared__ __align__(16) u16 As[TM * 32];
    __shared__ __align__(16) u16 Bs[128 * 32];
    const int bz = blockIdx.z;
    const int m0 = blockIdx.y * TM, n0 = blockIdx.x * 128;
    const u16* Ab = A + (size_t)bz * sA + (size_t)m0 * ldA;
    const u16* Bb = B + (size_t)bz * sB + (size_t)n0 * ldB;
    const int tid = threadIdx.x, lane = tid & 63, w = tid >> 6;
    const int wm = (w & 1) * (TM / 2);
    const int wn = (w >> 1) * 64;
    const int quad = lane >> 4, m16 = lane & 15;

    f32x4 acc[MI][4];
#pragma unroll
    for (int i = 0; i < MI; ++i)
#pragma unroll
        for (int j = 0; j < 4; ++j) acc[i][j] = (f32x4){0.f, 0.f, 0.f, 0.f};

    const int L0 = 2 * w * 64 + lane, L1 = L0 + 64;
    const int br0 = L0 >> 2, bc0 = (L0 & 3) * 8;
    const int br1 = L1 >> 2, bc1 = (L1 & 3) * 8;
    const int ar0 = (TM == 128) ? br0 : (tid >> 2);
    const int ac0 = (TM == 128) ? bc0 : (tid & 3) * 8;

    for (int k0 = 0; k0 < K; k0 += 32) {
        if (TM == 128) {
            load_lds16(Ab + (size_t)ar0 * ldA + k0 + ac0, &As[2 * w * 512]);
            load_lds16(Ab + (size_t)br1 * ldA + k0 + bc1, &As[(2 * w + 1) * 512]);
        } else {
            load_lds16(Ab + (size_t)ar0 * ldA + k0 + ac0, &As[w * 512]);
        }
        load_lds16(Bb + (size_t)br0 * ldB + k0 + bc0, &Bs[2 * w * 512]);
        load_lds16(Bb + (size_t)br1 * ldB + k0 + bc1, &Bs[(2 * w + 1) * 512]);
        __syncthreads();

        short8 af[MI], bfv[4];
#pragma unroll
        for (int i = 0; i < MI; ++i)
            af[i] = *(const short8*)&As[(wm + i * 16 + m16) * 32 + quad * 8];
#pragma unroll
        for (int j = 0; j < 4; ++j)
            bfv[j] = *(const short8*)&Bs[(wn + j * 16 + m16) * 32 + quad * 8];
#pragma unroll
        for (int i = 0; i < MI; ++i)
#pragma unroll
            for (int j = 0; j < 4; ++j)
                acc[i][j] = __builtin_amdgcn_mfma_f32_16x16x32_bf16(
                    af[i], bfv[j], acc[i][j], 0, 0, 0);
        __syncthreads();
    }

    if (bias_mode) {
#pragma unroll
        for (int i = 0; i < MI; ++i)
#pragma unroll
            for (int j = 0; j < 4; ++j)
#pragma unroll
                for (int r = 0; r < 4; ++r)
                    acc[i][j][r] += (bias_mode == 2)
                        ? bias[m0 + wm + i * 16 + quad * 4 + r]
                        : bias[n0 + wn + j * 16 + m16];
    }

    if (STORE == 0) {
        u16* C = (u16*)Cout + (size_t)bz * sC;
#pragma unroll
        for (int i = 0; i < MI; ++i) {
            int m = m0 + wm + i * 16 + quad * 4;
#pragma unroll
            for (int j = 0; j < 4; ++j) {
                int n = n0 + wn + j * 16 + m16;
#pragma unroll
                for (int r = 0; r < 4; ++r)
                    C[(size_t)(m + r) * ldC + n] = f2bf(acc[i][j][r]);
            }
        }
    } else {
        float* C = (float*)Cout + (size_t)bz * sC;
#pragma unroll
        for (int i = 0; i < MI; ++i) {
            int m = m0 + wm + i * 16 + quad * 4;
#pragma unroll
            for (int j = 0; j < 4; ++j) {
                int n = n0 + wn + j * 16 + m16;
#pragma unroll
                for (int r = 0; r < 4; ++r)
                    C[(size_t)(m + r) * ldC + n] = acc[i][j][r];
            }
        }
    }

    if (STATS) {
#pragma unroll
        for (int i = 0; i < MI; ++i) {
#pragma unroll
            for (int r = 0; r < 4; ++r) {
                float v0 = 0.f, v1 = 0.f;
#pragma unroll
                for (int j = 0; j < 4; ++j) {
                    float v = acc[i][j][r];
                    v0 += v;
                    v1 = fmaf(v, v, v1);
                }
#pragma unroll
                for (int off = 8; off; off >>= 1) {
                    v0 += __shfl_down(v0, off, 16);
                    v1 += __shfl_down(v1, off, 16);
                }
                if (m16 == 0) {
                    int m = m0 + wm + i * 16 + quad * 4 + r;
                    atomicAdd(&s0g[m], v0);
                    atomicAdd(&s1g[m], v1);
                }
            }
        }
    }
}

// ---------------------------------------------------------------------------
// PV GEMM with fused online softmax on the A side.
//   A = S raw scores (B, HW, HW) bf16; B = g (B, IC, HW) bf16;
//   y[q][ic] = sum_k softmax_k(S[q][:])[k] * g[ic][k]   -> (B, HW, IC) bf16
// 64x128 tile (TM=64 path of mfma_gemm) + flash-style running (m,l) per row.
// Row r of subtile i lives in 16-lane groups (m16); quads hold k-chunks ->
// cross-quad reduce = __shfl_xor 16/32; acc-row values fetched via 16-wide shfl.
// ---------------------------------------------------------------------------
__global__ __launch_bounds__(256, 2)
void pv_gemm(const u16* __restrict__ S, const u16* __restrict__ g,
             u16* __restrict__ y) {
    __shared__ __align__(16) u16 As[64 * 32];
    __shared__ __align__(16) u16 Bs[128 * 32];
    const int bz = blockIdx.z;
    const int m0 = blockIdx.y * 64, n0 = blockIdx.x * 128;
    const u16* Ab = S + (size_t)bz * HWc * HWc + (size_t)m0 * HWc;
    const u16* Bb = g + (size_t)bz * ICc * HWc + (size_t)n0 * HWc;
    const int tid = threadIdx.x, lane = tid & 63, w = tid >> 6;
    const int wm = (w & 1) * 32;
    const int wn = (w >> 1) * 64;
    const int quad = lane >> 4, m16 = lane & 15;

    f32x4 acc[2][4];
#pragma unroll
    for (int i = 0; i < 2; ++i)
#pragma unroll
        for (int j = 0; j < 4; ++j) acc[i][j] = (f32x4){0.f, 0.f, 0.f, 0.f};
    float mrow[2] = {-1e30f, -1e30f};
    float lrow[2] = {0.f, 0.f};

    const int ar0 = tid >> 2, ac0 = (tid & 3) * 8;
    const int L0 = 2 * w * 64 + lane, L1 = L0 + 64;
    const int br0 = L0 >> 2, bc0 = (L0 & 3) * 8;
    const int br1 = L1 >> 2, bc1 = (L1 & 3) * 8;

    for (int k0 = 0; k0 < HWc; k0 += 32) {
        load_lds16(Ab + (size_t)ar0 * HWc + k0 + ac0, &As[w * 512]);
        load_lds16(Bb + (size_t)br0 * HWc + k0 + bc0, &Bs[2 * w * 512]);
        load_lds16(Bb + (size_t)br1 * HWc + k0 + bc1, &Bs[(2 * w + 1) * 512]);
        __syncthreads();

        // ---- A-frags as fp32, online softmax per row (row = m16 of subtile i)
        short8 pf[2];
#pragma unroll
        for (int i = 0; i < 2; ++i) {
            short8 a8 = *(const short8*)&As[(wm + i * 16 + m16) * 32 + quad * 8];
            float av[8];
#pragma unroll
            for (int j = 0; j < 8; ++j) av[j] = bf2f((u16)a8[j]);
            float tm = av[0];
#pragma unroll
            for (int j = 1; j < 8; ++j) tm = fmaxf(tm, av[j]);
            tm = fmaxf(tm, __shfl_xor(tm, 16, 64));      // reduce over quads
            tm = fmaxf(tm, __shfl_xor(tm, 32, 64));
            float nm = fmaxf(mrow[i], tm);
            float alpha = __expf(mrow[i] - nm);
            mrow[i] = nm;
            float ps = 0.f;
#pragma unroll
            for (int j = 0; j < 8; ++j) {
                float p = __expf(av[j] - nm);
                pf[i][j] = (short)f2bf(p);
                ps += p;
            }
            ps += __shfl_xor(ps, 16, 64);
            ps += __shfl_xor(ps, 32, 64);
            lrow[i] = lrow[i] * alpha + ps;
            // rescale accumulator rows (acc row = quad*4 + r, uniform over quads)
#pragma unroll
            for (int r = 0; r < 4; ++r) {
                float ar = __shfl(alpha, quad * 4 + r, 16);
#pragma unroll
                for (int j = 0; j < 4; ++j) acc[i][j][r] *= ar;
            }
        }

        short8 bfv[4];
#pragma unroll
        for (int j = 0; j < 4; ++j)
            bfv[j] = *(const short8*)&Bs[(wn + j * 16 + m16) * 32 + quad * 8];
#pragma unroll
        for (int i = 0; i < 2; ++i)
#pragma unroll
            for (int j = 0; j < 4; ++j)
                acc[i][j] = __builtin_amdgcn_mfma_f32_16x16x32_bf16(
                    pf[i], bfv[j], acc[i][j], 0, 0, 0);
        __syncthreads();
    }

    // ---- epilogue: normalize rows by 1/l, store y (B,HW,IC) ----
#pragma unroll
    for (int i = 0; i < 2; ++i) {
        float rl = 1.0f / lrow[i];
#pragma unroll
        for (int r = 0; r < 4; ++r) {
            float rr = __shfl(rl, quad * 4 + r, 16);
            int m = m0 + wm + i * 16 + quad * 4 + r;
#pragma unroll
            for (int j = 0; j < 4; ++j) {
                int n = n0 + wn + j * 16 + m16;
                y[((size_t)bz * HWc + m) * ICc + n] = f2bf(acc[i][j][r] * rr);
            }
        }
    }
}

// ---------------------------------------------------------------------------
// Normalize (from raw sums) + affine + residual, float4 vectorized
// ---------------------------------------------------------------------------
__global__ __launch_bounds__(256)
void bn_apply(const float* __restrict__ wy, const float* __restrict__ x,
              const float* __restrict__ s0, const float* __restrict__ s1,
              const float* __restrict__ gamma, const float* __restrict__ beta,
              float* __restrict__ out) {
    const size_t i4 = (size_t)blockIdx.x * 256 + threadIdx.x;
    const size_t base = i4 * 4;
    const int o = (int)((base / HWc) % Cc);
    const float N = (float)(Bn * HWc);
    const float mean = s0[o] / N;
    const float var  = s1[o] / N - mean * mean;
    const float rstd = rsqrtf(var + BN_EPS);
    const float ga = gamma[o];
    const float be = beta[o];
    const float4 w4 = ((const float4*)wy)[i4];
    const float4 x4 = ((const float4*)x)[i4];
    float4 r;
    r.x = (w4.x - mean) * rstd * ga + be + x4.x;
    r.y = (w4.y - mean) * rstd * ga + be + x4.y;
    r.z = (w4.z - mean) * rstd * ga + be + x4.z;
    r.w = (w4.w - mean) * rstd * ga + be + x4.w;
    ((float4*)out)[i4] = r;
}

// ---------------------------------------------------------------------------
extern "C" void kernel_launch(void* const* d_in, const int* in_sizes, int n_in,
                              void* d_out, int out_size, void* d_ws, size_t ws_size,
                              hipStream_t stream) {
    const float* x     = (const float*)d_in[0];
    const float* g_w   = (const float*)d_in[1];
    const float* g_b   = (const float*)d_in[2];
    const float* th_w  = (const float*)d_in[3];
    const float* th_b  = (const float*)d_in[4];
    const float* ph_w  = (const float*)d_in[5];
    const float* ph_b  = (const float*)d_in[6];
    const float* w_w   = (const float*)d_in[7];
    const float* w_b   = (const float*)d_in[8];
    const float* gamma = (const float*)d_in[9];
    const float* beta  = (const float*)d_in[10];

    // Workspace aliasing (113.25 MB peak, same as proven round-4 layout):
    //  [0, 18.87M)      thph bf16 (B,HW,512)  -> post-S: y bf16 at [0,9.44M),
    //                   wbf2+stats at [9.44M,...)
    //  [18.87M, 28.31M) g bf16 (B,IC,HW)
    //  [28.31M, 113.25M) Sreg: pre-S hosts xt bf16 (B,HW,C) + wcat + bias_thph;
    //                   then S bf16 (B,HW,HW); post-PV wy fp32 (B,C,HW)
    char* base = (char*)d_ws;
    const size_t SZT = (size_t)Bn * HWc * ICc * 2;        // 9,437,184
    u16* thph = (u16*)base;                               // 18.87 MB
    u16* g    = (u16*)(base + 2 * SZT);                   // 9.44 MB
    char* Sreg = base + 3 * SZT;
    u16* S    = (u16*)Sreg;                               // 84.93 MB
    u16* xt   = (u16*)Sreg;                               // 18.87 MB (pre-S)
    u16* wcat = (u16*)(Sreg + (size_t)Bn * HWc * Cc * 2); // 786 KB (pre-S)
    float* bias_thph = (float*)(Sreg + (size_t)Bn * HWc * Cc * 2 + 786432);
    u16* y    = (u16*)base;                               // 9.44 MB (post-S)
    u16* wbf2 = (u16*)(base + SZT);                       // 262 KB (post-S)
    float* stats = (float*)(base + SZT + 262144);         // 4 KB (post-S)
    float* wy = (float*)Sreg;                             // 37.75 MB (post-PV)

    dim3 blk(256);
    const u16* thphw = wcat;                   // (512,512)
    const u16* gwb   = wcat + 262144;          // (256,512)

    cast_front<<<dim3(386), blk, 0, stream>>>(th_w, ph_w, g_w, th_b, ph_b,
                                              wcat, bias_thph);
    transpose_cast_x<<<dim3(HWc / 32, Cc / 64, Bn), blk, 0, stream>>>(x, xt);

    // thph[q][o] = sum_c xt[q][c]*thph_w[o][c] + bias  (M=2304,N=512,K=512)
    mfma_gemm<128, 0, false><<<dim3(4, 18, Bn), blk, 0, stream>>>(
        xt, thphw, thph, bias_thph, 1, Cc, Cc, Cc, 512,
        (size_t)HWc * Cc, 0, (size_t)HWc * 512, nullptr, nullptr);

    // g[ic][p] = sum_c g_w[ic][c]*xt[p][c] + g_b[ic]   (M=256,N=2304,K=512)
    mfma_gemm<64, 0, false><<<dim3(18, 4, Bn), blk, 0, stream>>>(
        gwb, xt, g, g_b, 2, Cc, Cc, Cc, HWc,
        0, (size_t)HWc * Cc, (size_t)ICc * HWc, nullptr, nullptr);

    // S = tht . pht^T (raw scores; M=N=2304, K=256); tht = thph cols 0..255
    mfma_gemm<128, 0, false><<<dim3(18, 18, Bn), blk, 0, stream>>>(
        thph, thph + 256, S, nullptr, 0, ICc, 512, 512, HWc,
        (size_t)HWc * 512, (size_t)HWc * 512, (size_t)HWc * HWc,
        nullptr, nullptr);

    // w_w -> bf16 and zero stats (into regions dead after S-gemm)
    cast_w<<<dim3(128), blk, 0, stream>>>(w_w, wbf2);
    hipMemsetAsync(stats, 0, 2 * Cc * sizeof(float), stream);

    // y[q][ic] = softmax-weighted sum over keys (fused online softmax in PV)
    pv_gemm<<<dim3(ICc / 128, HWc / 64, Bn), blk, 0, stream>>>(S, g, y);

    // wy[o][p] = sum_ic w_w[o][ic]*y[p][ic] + w_b[o]  (M=512,N=2304,K=256)
    // fp32 out + fused BN sum/sumsq
    mfma_gemm<128, 1, true><<<dim3(18, 4, Bn), blk, 0, stream>>>(
        wbf2, y, wy, w_b, 2, ICc, ICc, ICc, HWc,
        0, (size_t)HWc * ICc, (size_t)Cc * HWc, stats, stats + Cc);

    // BatchNorm apply (stats from raw sums) + affine + residual
    bn_apply<<<dim3((Bn * Cc * HWc) / 4 / 256), blk, 0, stream>>>(
        wy, x, stats, stats + Cc, gamma, beta, (float*)d_out);
}

// Round 8
// 353.850 us; speedup vs baseline: 1.1051x; 1.0959x over previous
//
#include <hip/hip_runtime.h>
#include <hip/hip_bf16.h>
#include <stdint.h>

// Problem constants (fixed by setup_inputs)
constexpr int Bn  = 8;
constexpr int Cc  = 512;
constexpr int ICc = 256;
constexpr int HWc = 48 * 48;           // 2304
constexpr float BN_EPS = 1e-5f;
constexpr float LOG2E = 1.44269504088896340736f;

typedef unsigned short u16;
typedef __attribute__((ext_vector_type(8))) short short8;   // 8 bf16 (4 VGPRs)
typedef __attribute__((ext_vector_type(4))) float f32x4;    // MFMA C/D frag

__device__ __forceinline__ u16 f2bf(float f) {
    uint32_t u = __builtin_bit_cast(uint32_t, f);
    u += 0x7fffu + ((u >> 16) & 1u);     // RNE
    return (u16)(u >> 16);
}
__device__ __forceinline__ float bf2f(u16 h) {
    uint32_t u = ((uint32_t)h) << 16;
    return __builtin_bit_cast(float, u);
}
// async global->LDS, 16B per lane; lds dst is wave-uniform base (HW adds lane*16)
__device__ __forceinline__ void load_lds16(const void* g, void* l) {
    __builtin_amdgcn_global_load_lds(
        (const __attribute__((address_space(1))) void*)(uintptr_t)g,
        (__attribute__((address_space(3))) void*)(uintptr_t)l, 16, 0, 0);
}

// ---------------------------------------------------------------------------
// Front cast: thph_w bf16 (rows 0..255=th_w, 256..511=ph_w), g_w bf16,
// bias_thph fp32 [th_b | ph_b].
// ---------------------------------------------------------------------------
__global__ __launch_bounds__(256)
void cast_front(const float* __restrict__ th_w, const float* __restrict__ ph_w,
                const float* __restrict__ g_w, const float* __restrict__ th_b,
                const float* __restrict__ ph_b, u16* __restrict__ wcat,
                float* __restrict__ bias_thph) {
    int idx = blockIdx.x * 256 + threadIdx.x;
    if (idx < 98304) {                           // ushort4 casts
        const float4* src;
        if (idx < 32768)       src = (const float4*)th_w + idx;
        else if (idx < 65536)  src = (const float4*)ph_w + (idx - 32768);
        else                   src = (const float4*)g_w  + (idx - 65536);
        float4 v = *src;
        ushort4 o;
        o.x = f2bf(v.x); o.y = f2bf(v.y); o.z = f2bf(v.z); o.w = f2bf(v.w);
        ((ushort4*)wcat)[idx] = o;
    } else if (idx < 98816) {                    // 512 bias floats
        int i = idx - 98304;
        bias_thph[i] = (i < 256) ? th_b[i] : ph_b[i - 256];
    }
}

__global__ __launch_bounds__(256)
void cast_w(const float* __restrict__ a, u16* __restrict__ out) {
    int idx = blockIdx.x * 256 + threadIdx.x;    // 0..32767
    float4 v = ((const float4*)a)[idx];
    ushort4 o;
    o.x = f2bf(v.x); o.y = f2bf(v.y); o.z = f2bf(v.z); o.w = f2bf(v.w);
    ((ushort4*)out)[idx] = o;
}

// ---------------------------------------------------------------------------
// x (B,C,HW) fp32 -> xt (B,HW,C) bf16, 64c x 32p LDS-tiled, ushort2 stores
// ---------------------------------------------------------------------------
__global__ __launch_bounds__(256)
void transpose_cast_x(const float* __restrict__ x, u16* __restrict__ xt) {
    __shared__ float t[64][33];
    const int b = blockIdx.z;
    const int p0 = blockIdx.x * 32;     // HW dir
    const int c0 = blockIdx.y * 64;     // C dir
    const int tx = threadIdx.x & 31, ty = threadIdx.x >> 5;   // ty 0..7
    const float* xb = x + (size_t)b * Cc * HWc;
#pragma unroll
    for (int r = 0; r < 8; ++r)
        t[r * 8 + ty][tx] = xb[(size_t)(c0 + r * 8 + ty) * HWc + p0 + tx];
    __syncthreads();
    u16* xtb = xt + (size_t)b * HWc * Cc;
    const int cc = (threadIdx.x & 31) * 2, pp = threadIdx.x >> 5;
#pragma unroll
    for (int r = 0; r < 4; ++r) {
        int p = r * 8 + pp;
        ushort2 v;
        v.x = f2bf(t[cc][p]);
        v.y = f2bf(t[cc + 1][p]);
        *(ushort2*)&xtb[(size_t)(p0 + p) * Cc + c0 + cc] = v;
    }
}

// ---------------------------------------------------------------------------
// bf16 MFMA GEMM: C[m][n] = sum_k A[m][k] * B[n][k] (+ bias), bf16 C out.
// Coalesced epilogue: per-wave LDS restage (stride 72 u16, 16B-aligned rows)
// -> dwordx4 global stores. STATS: fused BN sum/sumsq per m (fp32 acc).
// ---------------------------------------------------------------------------
template <int TM, bool STATS>
__global__ __launch_bounds__(256, 2)
void mfma_gemm(const u16* __restrict__ A, const u16* __restrict__ B,
               u16* __restrict__ Cout, const float* __restrict__ bias,
               int bias_mode, int K, int ldA, int ldB, int ldC,
               size_t sA, size_t sB, size_t sC,
               float* __restrict__ s0g, float* __restrict__ s1g) {
    constexpr int MI = TM / 32;                  // 4 (TM=128) or 2 (TM=64)
    constexpr int STG = (TM + 128) * 32;         // staging u16
    constexpr int EPI = 4 * (TM / 2) * 72;       // epilogue u16
    constexpr int SM  = STG > EPI ? STG : EPI;
    __shared__ __align__(16) u16 smem[SM];
    u16* As = smem;
    u16* Bs = smem + TM * 32;
    const int bz = blockIdx.z;
    const int m0 = blockIdx.y * TM, n0 = blockIdx.x * 128;
    const u16* Ab = A + (size_t)bz * sA + (size_t)m0 * ldA;
    const u16* Bb = B + (size_t)bz * sB + (size_t)n0 * ldB;
    const int tid = threadIdx.x, lane = tid & 63, w = tid >> 6;
    const int wm = (w & 1) * (TM / 2);
    const int wn = (w >> 1) * 64;
    const int quad = lane >> 4, m16 = lane & 15;

    f32x4 acc[MI][4];
#pragma unroll
    for (int i = 0; i < MI; ++i)
#pragma unroll
        for (int j = 0; j < 4; ++j) acc[i][j] = (f32x4){0.f, 0.f, 0.f, 0.f};

    const int L0 = 2 * w * 64 + lane, L1 = L0 + 64;
    const int br0 = L0 >> 2, bc0 = (L0 & 3) * 8;
    const int br1 = L1 >> 2, bc1 = (L1 & 3) * 8;
    const int ar0 = (TM == 128) ? br0 : (tid >> 2);
    const int ac0 = (TM == 128) ? bc0 : (tid & 3) * 8;

    for (int k0 = 0; k0 < K; k0 += 32) {
        if (TM == 128) {
            load_lds16(Ab + (size_t)ar0 * ldA + k0 + ac0, &As[2 * w * 512]);
            load_lds16(Ab + (size_t)br1 * ldA + k0 + bc1, &As[(2 * w + 1) * 512]);
        } else {
            load_lds16(Ab + (size_t)ar0 * ldA + k0 + ac0, &As[w * 512]);
        }
        load_lds16(Bb + (size_t)br0 * ldB + k0 + bc0, &Bs[2 * w * 512]);
        load_lds16(Bb + (size_t)br1 * ldB + k0 + bc1, &Bs[(2 * w + 1) * 512]);
        __syncthreads();

        short8 af[MI], bfv[4];
#pragma unroll
        for (int i = 0; i < MI; ++i)
            af[i] = *(const short8*)&As[(wm + i * 16 + m16) * 32 + quad * 8];
#pragma unroll
        for (int j = 0; j < 4; ++j)
            bfv[j] = *(const short8*)&Bs[(wn + j * 16 + m16) * 32 + quad * 8];
#pragma unroll
        for (int i = 0; i < MI; ++i)
#pragma unroll
            for (int j = 0; j < 4; ++j)
                acc[i][j] = __builtin_amdgcn_mfma_f32_16x16x32_bf16(
                    af[i], bfv[j], acc[i][j], 0, 0, 0);
        __syncthreads();
    }

    if (bias_mode) {
#pragma unroll
        for (int i = 0; i < MI; ++i)
#pragma unroll
            for (int j = 0; j < 4; ++j)
#pragma unroll
                for (int r = 0; r < 4; ++r)
                    acc[i][j][r] += (bias_mode == 2)
                        ? bias[m0 + wm + i * 16 + quad * 4 + r]
                        : bias[n0 + wn + j * 16 + m16];
    }

    if (STATS) {
#pragma unroll
        for (int i = 0; i < MI; ++i) {
#pragma unroll
            for (int r = 0; r < 4; ++r) {
                float v0 = 0.f, v1 = 0.f;
#pragma unroll
                for (int j = 0; j < 4; ++j) {
                    float v = acc[i][j][r];
                    v0 += v;
                    v1 = fmaf(v, v, v1);
                }
#pragma unroll
                for (int off = 8; off; off >>= 1) {
                    v0 += __shfl_down(v0, off, 16);
                    v1 += __shfl_down(v1, off, 16);
                }
                if (m16 == 0) {
                    int m = m0 + wm + i * 16 + quad * 4 + r;
                    atomicAdd(&s0g[m], v0);
                    atomicAdd(&s1g[m], v1);
                }
            }
        }
    }

    // ---- coalesced epilogue: per-wave LDS restage -> dwordx4 stores ----
    u16* ep = smem + w * (TM / 2) * 72;
#pragma unroll
    for (int i = 0; i < MI; ++i)
#pragma unroll
        for (int j = 0; j < 4; ++j)
#pragma unroll
            for (int r = 0; r < 4; ++r)
                ep[(i * 16 + quad * 4 + r) * 72 + j * 16 + m16] =
                    f2bf(acc[i][j][r]);
    u16* C = Cout + (size_t)bz * sC;
#pragma unroll
    for (int p = 0; p < TM / 16; ++p) {
        int lr = p * 8 + (lane >> 3), col = (lane & 7) * 8;
        short8 v = *(const short8*)&ep[lr * 72 + col];
        *(short8*)&C[(size_t)(m0 + wm + lr) * ldC + n0 + wn + col] = v;
    }
}

// ---------------------------------------------------------------------------
// rowstat: per row of S, c = m + ln(sum exp(s - m)). One wave per row.
// ---------------------------------------------------------------------------
__global__ __launch_bounds__(256)
void rowstat(const u16* __restrict__ S, float* __restrict__ crow) {
    const int row = blockIdx.x * 4 + (threadIdx.x >> 6);   // 0..18431
    const int lane = threadIdx.x & 63;
    const uint2* r = (const uint2*)(S + (size_t)row * HWc);

    float v[36];
#pragma unroll
    for (int c = 0; c < 9; ++c) {
        uint2 d = r[lane + 64 * c];
        v[c * 4 + 0] = bf2f((u16)(d.x & 0xffff));
        v[c * 4 + 1] = bf2f((u16)(d.x >> 16));
        v[c * 4 + 2] = bf2f((u16)(d.y & 0xffff));
        v[c * 4 + 3] = bf2f((u16)(d.y >> 16));
    }
    float m = v[0];
#pragma unroll
    for (int i = 1; i < 36; ++i) m = fmaxf(m, v[i]);
#pragma unroll
    for (int off = 32; off; off >>= 1) m = fmaxf(m, __shfl_xor(m, off, 64));
    float s = 0.f;
#pragma unroll
    for (int i = 0; i < 36; ++i) s += __expf(v[i] - m);
#pragma unroll
    for (int off = 32; off; off >>= 1) s += __shfl_xor(s, off, 64);
    if (lane == 0) crow[row] = m + __logf(s);
}

// ---------------------------------------------------------------------------
// PV GEMM with precomputed softmax constant: p = exp(s - crow) (no reductions).
//   A = S raw (B,HW,HW) bf16; B = g (B,IC,HW); y (B,HW,IC) bf16.
// TM=64 x TN=128 tile, coalesced LDS epilogue.
// ---------------------------------------------------------------------------
__global__ __launch_bounds__(256, 2)
void pv_gemm(const u16* __restrict__ S, const u16* __restrict__ g,
             const float* __restrict__ crow, u16* __restrict__ y) {
    __shared__ __align__(16) u16 smem[4 * 32 * 72];        // epi 9216 > stg 6144
    u16* As = smem;
    u16* Bs = smem + 64 * 32;
    const int bz = blockIdx.z;
    const int m0 = blockIdx.y * 64, n0 = blockIdx.x * 128;
    const u16* Ab = S + (size_t)bz * HWc * HWc + (size_t)m0 * HWc;
    const u16* Bb = g + (size_t)bz * ICc * HWc + (size_t)n0 * HWc;
    const int tid = threadIdx.x, lane = tid & 63, w = tid >> 6;
    const int wm = (w & 1) * 32;
    const int wn = (w >> 1) * 64;
    const int quad = lane >> 4, m16 = lane & 15;

    // per-lane softmax constants (row = wm + i*16 + m16), pre-scaled by log2e
    float c2[2];
#pragma unroll
    for (int i = 0; i < 2; ++i)
        c2[i] = crow[(size_t)bz * HWc + m0 + wm + i * 16 + m16] * LOG2E;

    f32x4 acc[2][4];
#pragma unroll
    for (int i = 0; i < 2; ++i)
#pragma unroll
        for (int j = 0; j < 4; ++j) acc[i][j] = (f32x4){0.f, 0.f, 0.f, 0.f};

    const int ar0 = tid >> 2, ac0 = (tid & 3) * 8;
    const int L0 = 2 * w * 64 + lane, L1 = L0 + 64;
    const int br0 = L0 >> 2, bc0 = (L0 & 3) * 8;
    const int br1 = L1 >> 2, bc1 = (L1 & 3) * 8;

    for (int k0 = 0; k0 < HWc; k0 += 32) {
        load_lds16(Ab + (size_t)ar0 * HWc + k0 + ac0, &As[w * 512]);
        load_lds16(Bb + (size_t)br0 * HWc + k0 + bc0, &Bs[2 * w * 512]);
        load_lds16(Bb + (size_t)br1 * HWc + k0 + bc1, &Bs[(2 * w + 1) * 512]);
        __syncthreads();

        short8 pf[2], bfv[4];
#pragma unroll
        for (int i = 0; i < 2; ++i) {
            short8 a8 = *(const short8*)&As[(wm + i * 16 + m16) * 32 + quad * 8];
#pragma unroll
            for (int j = 0; j < 8; ++j) {
                float f = bf2f((u16)a8[j]);
                float p = exp2f(__builtin_fmaf(f, LOG2E, -c2[i]));
                pf[i][j] = (short)(u16)(__builtin_bit_cast(uint32_t, p) >> 16);
            }
        }
#pragma unroll
        for (int j = 0; j < 4; ++j)
            bfv[j] = *(const short8*)&Bs[(wn + j * 16 + m16) * 32 + quad * 8];
#pragma unroll
        for (int i = 0; i < 2; ++i)
#pragma unroll
            for (int j = 0; j < 4; ++j)
                acc[i][j] = __builtin_amdgcn_mfma_f32_16x16x32_bf16(
                    pf[i], bfv[j], acc[i][j], 0, 0, 0);
        __syncthreads();
    }

    // ---- coalesced epilogue (per-wave LDS restage) ----
    u16* ep = smem + w * 32 * 72;
#pragma unroll
    for (int i = 0; i < 2; ++i)
#pragma unroll
        for (int j = 0; j < 4; ++j)
#pragma unroll
            for (int r = 0; r < 4; ++r)
                ep[(i * 16 + quad * 4 + r) * 72 + j * 16 + m16] =
                    f2bf(acc[i][j][r]);
#pragma unroll
    for (int p = 0; p < 4; ++p) {
        int lr = p * 8 + (lane >> 3), col = (lane & 7) * 8;
        short8 v = *(const short8*)&ep[lr * 72 + col];
        *(short8*)&y[((size_t)bz * HWc + m0 + wm + lr) * ICc + wn + col] = v;
    }
}

// ---------------------------------------------------------------------------
// Normalize (from raw sums) + affine + residual; wy is bf16, out fp32
// ---------------------------------------------------------------------------
__global__ __launch_bounds__(256)
void bn_apply(const u16* __restrict__ wy, const float* __restrict__ x,
              const float* __restrict__ s0, const float* __restrict__ s1,
              const float* __restrict__ gamma, const float* __restrict__ beta,
              float* __restrict__ out) {
    const size_t i4 = (size_t)blockIdx.x * 256 + threadIdx.x;
    const size_t base = i4 * 4;
    const int o = (int)((base / HWc) % Cc);
    const float N = (float)(Bn * HWc);
    const float mean = s0[o] / N;
    const float var  = s1[o] / N - mean * mean;
    const float rstd = rsqrtf(var + BN_EPS);
    const float ga = gamma[o];
    const float be = beta[o];
    uint2 d = ((const uint2*)wy)[i4];
    float w0 = bf2f((u16)(d.x & 0xffff)), w1 = bf2f((u16)(d.x >> 16));
    float w2 = bf2f((u16)(d.y & 0xffff)), w3 = bf2f((u16)(d.y >> 16));
    const float4 x4 = ((const float4*)x)[i4];
    float4 r;
    r.x = (w0 - mean) * rstd * ga + be + x4.x;
    r.y = (w1 - mean) * rstd * ga + be + x4.y;
    r.z = (w2 - mean) * rstd * ga + be + x4.z;
    r.w = (w3 - mean) * rstd * ga + be + x4.w;
    ((float4*)out)[i4] = r;
}

// ---------------------------------------------------------------------------
extern "C" void kernel_launch(void* const* d_in, const int* in_sizes, int n_in,
                              void* d_out, int out_size, void* d_ws, size_t ws_size,
                              hipStream_t stream) {
    const float* x     = (const float*)d_in[0];
    const float* g_w   = (const float*)d_in[1];
    const float* g_b   = (const float*)d_in[2];
    const float* th_w  = (const float*)d_in[3];
    const float* th_b  = (const float*)d_in[4];
    const float* ph_w  = (const float*)d_in[5];
    const float* ph_b  = (const float*)d_in[6];
    const float* w_w   = (const float*)d_in[7];
    const float* w_b   = (const float*)d_in[8];
    const float* gamma = (const float*)d_in[9];
    const float* beta  = (const float*)d_in[10];

    // Workspace aliasing (113.25 MB peak, proven bound):
    //  [0, 18.87M)      thph bf16 (B,HW,512); post-S: y bf16 [0,9.44M),
    //                   wbf2+stats+crow at [9.44M, ...)
    //  [18.87M, 28.31M) g bf16 (B,IC,HW)
    //  [28.31M, 113.25M) Sreg: pre-S hosts xt + wcat + bias_thph;
    //                   then S bf16 (B,HW,HW); post-PV wy bf16 (B,C,HW)
    char* base = (char*)d_ws;
    const size_t SZT = (size_t)Bn * HWc * ICc * 2;        // 9,437,184
    u16* thph = (u16*)base;
    u16* g    = (u16*)(base + 2 * SZT);
    char* Sreg = base + 3 * SZT;
    u16* S    = (u16*)Sreg;                               // 84.93 MB
    u16* xt   = (u16*)Sreg;                               // 18.87 MB (pre-S)
    u16* wcat = (u16*)(Sreg + (size_t)Bn * HWc * Cc * 2); // 786 KB (pre-S)
    float* bias_thph = (float*)(Sreg + (size_t)Bn * HWc * Cc * 2 + 786432);
    u16* y    = (u16*)base;                               // 9.44 MB (post-S)
    u16* wbf2 = (u16*)(base + SZT);                       // 262 KB (post-S)
    float* stats = (float*)(base + SZT + 262144);         // 4 KB (post-S)
    float* crow  = (float*)(base + SZT + 262144 + 4096);  // 73,728 B (post-S)
    u16* wy = (u16*)Sreg;                                 // 18.87 MB (post-PV)

    dim3 blk(256);
    const u16* thphw = wcat;                   // (512,512)
    const u16* gwb   = wcat + 262144;          // (256,512)

    cast_front<<<dim3(386), blk, 0, stream>>>(th_w, ph_w, g_w, th_b, ph_b,
                                              wcat, bias_thph);
    transpose_cast_x<<<dim3(HWc / 32, Cc / 64, Bn), blk, 0, stream>>>(x, xt);

    // thph[q][o] = sum_c xt[q][c]*thph_w[o][c] + bias  (M=2304,N=512,K=512)
    mfma_gemm<128, false><<<dim3(4, 18, Bn), blk, 0, stream>>>(
        xt, thphw, thph, bias_thph, 1, Cc, Cc, Cc, 512,
        (size_t)HWc * Cc, 0, (size_t)HWc * 512, nullptr, nullptr);

    // g[ic][p] = sum_c g_w[ic][c]*xt[p][c] + g_b[ic]   (M=256,N=2304,K=512)
    mfma_gemm<64, false><<<dim3(18, 4, Bn), blk, 0, stream>>>(
        gwb, xt, g, g_b, 2, Cc, Cc, Cc, HWc,
        0, (size_t)HWc * Cc, (size_t)ICc * HWc, nullptr, nullptr);

    // S = tht . pht^T (raw scores; M=N=2304, K=256); tht = thph cols 0..255
    mfma_gemm<128, false><<<dim3(18, 18, Bn), blk, 0, stream>>>(
        thph, thph + 256, S, nullptr, 0, ICc, 512, 512, HWc,
        (size_t)HWc * 512, (size_t)HWc * 512, (size_t)HWc * HWc,
        nullptr, nullptr);

    // w_w -> bf16, zero stats, row softmax constants (dead-region hosted)
    cast_w<<<dim3(128), blk, 0, stream>>>(w_w, wbf2);
    hipMemsetAsync(stats, 0, 2 * Cc * sizeof(float), stream);
    rowstat<<<dim3(Bn * HWc / 4), blk, 0, stream>>>(S, crow);

    // y[q][ic] = sum_k exp(S[q][k]-crow[q]) * g[ic][k]
    pv_gemm<<<dim3(ICc / 128, HWc / 64, Bn), blk, 0, stream>>>(S, g, crow, y);

    // wy[o][p] = sum_ic w_w[o][ic]*y[p][ic] + w_b[o]  (M=512,N=2304,K=256)
    // bf16 out + fused BN sum/sumsq (fp32 acc)
    mfma_gemm<128, true><<<dim3(18, 4, Bn), blk, 0, stream>>>(
        wbf2, y, wy, w_b, 2, ICc, ICc, ICc, HWc,
        0, (size_t)HWc * ICc, (size_t)Cc * HWc, stats, stats + Cc);

    // BatchNorm apply (stats from raw sums) + affine + residual
    bn_apply<<<dim3((Bn * Cc * HWc) / 4 / 256), blk, 0, stream>>>(
        wy, x, stats, stats + Cc, gamma, beta, (float*)d_out);
}